// Round 10
// baseline (602.288 us; speedup 1.0000x reference)
//
#include <hip/hip_runtime.h>

#define N_NODES   50000
#define N_EDGES   1600000
#define FDIM_IN   128
#define HDIM      160
#define N_GRAPHS  512
#define BN_EPS    1e-5f
#define NBKT_MAX  128           // coarse dst buckets of 512 nodes (N<=65536)
#define DBINS     1024          // degree-sort bins

typedef short  frag8 __attribute__((ext_vector_type(8)));   // 8 x bf16
typedef float  facc4 __attribute__((ext_vector_type(4)));   // 4 x f32

// ---------------- bf16 helpers ----------------

__device__ __forceinline__ unsigned short f2bf(float f) {
    unsigned int u = __float_as_uint(f);
    return (unsigned short)((u + 0x7FFFu + ((u >> 16) & 1u)) >> 16);
}

__device__ __forceinline__ unsigned int pack2(float lo, float hi) {
    return (unsigned int)f2bf(lo) | ((unsigned int)f2bf(hi) << 16);
}

__device__ __forceinline__ void addpk8(float* acc, uint4 r) {
    acc[0] += __uint_as_float(r.x << 16);
    acc[1] += __uint_as_float(r.x & 0xFFFF0000u);
    acc[2] += __uint_as_float(r.y << 16);
    acc[3] += __uint_as_float(r.y & 0xFFFF0000u);
    acc[4] += __uint_as_float(r.z << 16);
    acc[5] += __uint_as_float(r.z & 0xFFFF0000u);
    acc[6] += __uint_as_float(r.w << 16);
    acc[7] += __uint_as_float(r.w & 0xFFFF0000u);
}

// ---------------- init: fixed-capacity bucket cursors + degree-hist zero ----------------

__global__ __launch_bounds__(1024) void init_kernel(int* __restrict__ bucket_cursor,
                                                    int* __restrict__ dhist,
                                                    int nbkt, int cap) {
    int t = threadIdx.x;
    if (t < nbkt) bucket_cursor[t] = t * cap;
    if (t < DBINS) dhist[t] = 0;
}

// level 1: partition packed (src<<9 | dst&511) into fixed-capacity bucket regions
__global__ __launch_bounds__(256) void part_kernel(const int* __restrict__ src,
                                                   const int* __restrict__ dst,
                                                   int* __restrict__ bucket_cursor,
                                                   unsigned int* __restrict__ pairs,
                                                   int E, int cap) {
    __shared__ int bcnt[NBKT_MAX], bbase[NBKT_MAX], lc[NBKT_MAX];
    int tid = threadIdx.x;
    int per = (E + gridDim.x - 1) / gridDim.x;
    int beg = blockIdx.x * per;
    int end = min(beg + per, E);
    if (tid < NBKT_MAX) { bcnt[tid] = 0; lc[tid] = 0; }
    __syncthreads();
    for (int e = beg + tid; e < end; e += 256)
        atomicAdd(&bcnt[dst[e] >> 9], 1);
    __syncthreads();
    if (tid < NBKT_MAX)
        bbase[tid] = bcnt[tid] ? atomicAdd(&bucket_cursor[tid], bcnt[tid]) : 0;
    __syncthreads();
    for (int e = beg + tid; e < end; e += 256) {
        int d = dst[e];
        int b = d >> 9;
        int pos = bbase[b] + atomicAdd(&lc[b], 1);
        if (pos < (b + 1) * cap)   // statistically impossible overflow guard
            pairs[pos] = ((unsigned int)src[e] << 9) | (unsigned int)(d & 511);
    }
}

// level 2: per-bucket exact CSR build + local scatter; emits row_off, deg, inv
__global__ __launch_bounds__(1024) void bucket_csr_kernel(const unsigned int* __restrict__ pairs,
                                                          const int* __restrict__ bucket_cursor,
                                                          int* __restrict__ row_off,
                                                          unsigned short* __restrict__ deg,
                                                          float* __restrict__ inv,
                                                          unsigned short* __restrict__ ssrc,
                                                          int n, int cap) {
    __shared__ int h[512];
    __shared__ int ws[8];
    int tid = threadIdx.x;
    int b = blockIdx.x;
    int node0 = b << 9;
    int beg = b * cap;
    int end = min(bucket_cursor[b], (b + 1) * cap);
    if (tid < 512) h[tid] = 0;
    __syncthreads();
    for (int j = beg + tid; j < end; j += 1024)
        atomicAdd(&h[pairs[j] & 511], 1);
    __syncthreads();
    int cntv = (tid < 512) ? h[tid] : 0;
    __syncthreads();
    int lane = tid & 63, wid = tid >> 6;
    int incl = cntv;
    #pragma unroll
    for (int off = 1; off < 64; off <<= 1) {
        int u = __shfl_up(incl, off);
        if (lane >= off) incl += u;
    }
    if (tid < 512 && lane == 63) ws[wid] = incl;
    __syncthreads();
    if (tid == 0) {
        int r = 0;
        #pragma unroll
        for (int i = 0; i < 8; ++i) { int t = ws[i]; ws[i] = r; r += t; }
    }
    __syncthreads();
    int excl = (tid < 512) ? (ws[wid] + incl - cntv) : 0;
    if (tid < 512) {
        int node = node0 + tid;
        if (node < n) {
            row_off[node] = beg + excl;
            deg[node] = (unsigned short)cntv;
            inv[node] = rsqrtf((float)(cntv + 1));   // +1 = self loop
        }
        h[tid] = excl;
    }
    __syncthreads();
    for (int j = beg + tid; j < end; j += 1024) {
        unsigned int p = pairs[j];
        int pos = beg + atomicAdd(&h[p & 511], 1);
        ssrc[pos] = (unsigned short)(p >> 9);
    }
}

// ---------------- degree ordering (counting sort of nodes by degree) ----------------

__global__ __launch_bounds__(256) void dhist_kernel(const unsigned short* __restrict__ deg,
                                                    int* __restrict__ dhist, int n) {
    __shared__ int h[DBINS];
    int tid = threadIdx.x;
    for (int i = tid; i < DBINS; i += 256) h[i] = 0;
    __syncthreads();
    for (int i = blockIdx.x * 256 + tid; i < n; i += gridDim.x * 256)
        atomicAdd(&h[min((int)deg[i], DBINS - 1)], 1);
    __syncthreads();
    for (int i = tid; i < DBINS; i += 256)
        if (h[i]) atomicAdd(&dhist[i], h[i]);
}

__global__ __launch_bounds__(1024) void dscan_kernel(const int* __restrict__ dhist,
                                                     int* __restrict__ dcursor) {
    __shared__ int ws[16];
    int t = threadIdx.x;
    int v = dhist[t];
    int lane = t & 63, wid = t >> 6;
    int incl = v;
    #pragma unroll
    for (int off = 1; off < 64; off <<= 1) {
        int u = __shfl_up(incl, off);
        if (lane >= off) incl += u;
    }
    if (lane == 63) ws[wid] = incl;
    __syncthreads();
    if (t == 0) {
        int r = 0;
        #pragma unroll
        for (int i = 0; i < 16; ++i) { int x = ws[i]; ws[i] = r; r += x; }
    }
    __syncthreads();
    dcursor[t] = ws[wid] + incl - v;    // exclusive prefix
}

__global__ __launch_bounds__(256) void dorder_kernel(const unsigned short* __restrict__ deg,
                                                     int* __restrict__ dcursor,
                                                     int* __restrict__ order, int n) {
    int i = blockIdx.x * 256 + threadIdx.x;
    if (i < n) {
        int bin = min((int)deg[i], DBINS - 1);
        int pos = atomicAdd(&dcursor[bin], 1);
        order[pos] = i;
    }
}

// ---------------- BN fold ----------------

__global__ void prep_kernel(const float* __restrict__ b, const float* __restrict__ g,
                            const float* __restrict__ be, const float* __restrict__ m,
                            const float* __restrict__ v, float* __restrict__ sc,
                            float* __restrict__ sh) {
    int t = threadIdx.x;
    if (t < HDIM) {
        float s = g[t] * rsqrtf(v[t] + BN_EPS);
        sc[t] = s;
        sh[t] = (b[t] - m[t]) * s + be[t];
    }
}

// ---------------- weight pack: W fp32 [K x 160] -> bf16 MFMA B-fragment order ----------------

template <int K>
__global__ __launch_bounds__(256) void pack_w_kernel(const float* __restrict__ W,
                                                     unsigned short* __restrict__ out) {
    int tid = blockIdx.x * 256 + threadIdx.x;
    if (tid >= K * 160) return;
    int j = tid & 7;
    int l = (tid >> 3) & 63;
    int u = (tid >> 9) % 10;
    int t = tid / 5120;
    int k = t * 32 + (l >> 4) * 8 + j;
    int nn = u * 16 + (l & 15);
    out[tid] = f2bf(W[k * 160 + nn]);
}

// ---------------- pre-scale + pack into 4 channel slabs (C=128, SLICE=32) ----------------

__global__ __launch_bounds__(256) void scale_slab_kernel(const float* __restrict__ x,
                                                         const float* __restrict__ inv,
                                                         unsigned short* __restrict__ slabs,
                                                         int n) {
    int i = blockIdx.x * 256 + threadIdx.x;      // float4 index over n*32
    if (i < n * 32) {
        int node = i >> 5;
        int f = i & 31;                          // float4 within row
        int s = f >> 3;                          // slice (8 float4 per slice)
        int o = f & 7;
        float w = inv[node];
        float4 v = ((const float4*)x)[i];
        ushort4 ov;
        ov.x = f2bf(v.x * w); ov.y = f2bf(v.y * w);
        ov.z = f2bf(v.z * w); ov.w = f2bf(v.w * w);
        *(ushort4*)(slabs + (size_t)s * n * 32 + (size_t)node * 32 + o * 4) = ov;
    }
}

// ---------------- XCD-affine slab aggregation, group-per-node, degree-sorted ----------------
// slabs: 4 slabs of N*SLICE bf16 (pre-scaled by inv[src]); SLICE = C/4.
// Each LPE-lane group owns ONE node (its whole slice row): no cross-group combine.
// Node assignment via degree-sorted order[] -> groups in a wave have ~equal trip
// counts. slice = blockIdx&3 keeps each XCD's gathers inside one <=4MB slab.

template <int C>
__global__ __launch_bounds__(256) void agg_slab2_kernel(const unsigned short* __restrict__ slabs,
                                                        const int* __restrict__ row_off,
                                                        const unsigned short* __restrict__ deg,
                                                        const int* __restrict__ order,
                                                        const unsigned short* __restrict__ ssrc,
                                                        unsigned short* __restrict__ out, int n) {
    constexpr int SLICE = C / 4;        // 40 or 32 channels
    constexpr int LPE   = SLICE / 8;    // lanes per node (uint4 = 8 ch): 5 or 4
    constexpr int G     = 64 / LPE;     // nodes per wave: 12 or 16
    int wave = threadIdx.x >> 6;
    int lane = threadIdx.x & 63;
    int slice = blockIdx.x & 3;
    int nb = blockIdx.x >> 2;
    int g  = lane / LPE;
    int cl = lane - g * LPE;
    const uint4* slab = (const uint4*)(slabs + (size_t)slice * n * SLICE);  // row = LPE uint4

    int gidx = nb * (4 * G) + wave * G + g;
    bool act = (g < G) && (gidx < n);
    int node = 0, beg = 0, dg = 0;
    if (act) {
        node = order[gidx];
        beg  = row_off[node];
        dg   = (int)deg[node];
    }
    float acc[8] = {0.f, 0.f, 0.f, 0.f, 0.f, 0.f, 0.f, 0.f};
    if (act) {   // self-loop term
        uint4 r = slab[(size_t)node * LPE + cl];
        addpk8(acc, r);
    }
    int j = 0;
    for (; j + 1 < dg; j += 2) {
        int s0 = ssrc[beg + j], s1 = ssrc[beg + j + 1];
        uint4 r0 = slab[(size_t)s0 * LPE + cl];
        uint4 r1 = slab[(size_t)s1 * LPE + cl];
        addpk8(acc, r0);
        addpk8(acc, r1);
    }
    if (j < dg) {
        uint4 r = slab[(size_t)ssrc[beg + j] * LPE + cl];
        addpk8(acc, r);
    }
    if (act) {
        float wi = rsqrtf((float)(dg + 1));
        uint4 o;
        o.x = pack2(acc[0] * wi, acc[1] * wi);
        o.y = pack2(acc[2] * wi, acc[3] * wi);
        o.z = pack2(acc[4] * wi, acc[5] * wi);
        o.w = pack2(acc[6] * wi, acc[7] * wi);
        *(uint4*)(out + (size_t)node * C + slice * SLICE + cl * 8) = o;
    }
}

// ---------------- MFMA GEMM: relu((A[n x K]bf16 @ B[K x 160]bf16) * sc + sh) ----------------
// OUTMODE 0: fp32 row-major out. OUTMODE 1: bf16 out scaled by inv[row], written to
// 4 channel slabs of SLICE=40 (layer-2/3 agg input layout).

template <int K, int OUTMODE>
__global__ __launch_bounds__(256) void mfma_gemm_kernel(const unsigned short* __restrict__ A,
                                                        const unsigned short* __restrict__ Bp,
                                                        const float* __restrict__ sc,
                                                        const float* __restrict__ sh,
                                                        const float* __restrict__ inv,
                                                        float* __restrict__ CoutF,
                                                        unsigned short* __restrict__ CoutB,
                                                        int n) {
    constexpr int KT = K / 32;
    int tid = threadIdx.x;
    int wave = tid >> 6, lane = tid & 63;
    int row0 = blockIdx.x * 64 + wave * 16;
    int m = lane & 15, q = lane >> 4;

    int arow = row0 + m;
    int arowc = (arow < n) ? arow : (n - 1);
    const frag8* Abase = (const frag8*)(A + (size_t)arowc * K);   // frag idx = t*4 + q
    const frag8* Bbase = (const frag8*)Bp;                        // frag idx = (t*10+u)*64 + lane

    facc4 acc[10];
    #pragma unroll
    for (int u = 0; u < 10; ++u) acc[u] = (facc4){0.f, 0.f, 0.f, 0.f};

    #pragma unroll
    for (int t = 0; t < KT; ++t) {
        frag8 af = Abase[t * 4 + q];
        #pragma unroll
        for (int u = 0; u < 10; ++u) {
            frag8 bf = Bbase[(t * 10 + u) * 64 + lane];
            acc[u] = __builtin_amdgcn_mfma_f32_16x16x32_bf16(af, bf, acc[u], 0, 0, 0);
        }
    }

    // D layout: col = lane&15 (within tile), row = q*4 + reg
    #pragma unroll
    for (int u = 0; u < 10; ++u) {
        int c = u * 16 + m;
        float scv = sc[c], shv = sh[c];
        int s = c / 40, o = c - s * 40;   // slab / offset (OUTMODE 1)
        #pragma unroll
        for (int r = 0; r < 4; ++r) {
            int rr = row0 + q * 4 + r;
            if (rr < n) {
                float v = fmaxf(acc[u][r] * scv + shv, 0.f);
                if (OUTMODE == 1) {
                    CoutB[(size_t)s * n * 40 + (size_t)rr * 40 + o] = f2bf(v * inv[rr]);
                } else {
                    CoutF[(size_t)rr * 160 + c] = v;
                }
            }
        }
    }
}

// ---------------- mean pool (sorted batch) + MLP head ----------------

__global__ __launch_bounds__(256) void pool_head_kernel(const float* __restrict__ h,
                                                        const int* __restrict__ batch,
                                                        const float* __restrict__ Wc1,
                                                        const float* __restrict__ bc1,
                                                        const float* __restrict__ Wc2,
                                                        const float* __restrict__ bc2,
                                                        float* __restrict__ out, int n) {
    __shared__ float pooled[160];
    __shared__ float z[80];
    __shared__ int range[2];
    int g = blockIdx.x;
    int t = threadIdx.x;
    if (t < 2) {
        int target = g + t;
        int lo = 0, hi = n;
        while (lo < hi) {
            int mid = (lo + hi) >> 1;
            if (batch[mid] < target) lo = mid + 1; else hi = mid;
        }
        range[t] = lo;
    }
    __syncthreads();
    int lo = range[0], hi = range[1];
    if (t < 160) {
        float s = 0.f;
        for (int r = lo; r < hi; ++r) s += h[(size_t)r * 160 + t];
        pooled[t] = s / fmaxf((float)(hi - lo), 1.f);
    }
    __syncthreads();
    if (t < 80) {
        float s = bc1[t];
        for (int k = 0; k < 160; ++k) s += pooled[k] * Wc1[k * 80 + t];
        z[t] = fmaxf(s, 0.f);
    }
    __syncthreads();
    if (t < 2) {
        float s = bc2[t];
        for (int k = 0; k < 80; ++k) s += z[k] * Wc2[k * 2 + t];
        out[g * 2 + t] = s;
    }
}

// ---------------- launch ----------------

static inline size_t align256(size_t x) { return (x + 255) & ~(size_t)255; }

extern "C" void kernel_launch(void* const* d_in, const int* in_sizes, int n_in,
                              void* d_out, int out_size, void* d_ws, size_t ws_size,
                              hipStream_t stream) {
    const float* x   = (const float*)d_in[0];
    const int* ei    = (const int*)d_in[1];
    const int* batch = (const int*)d_in[2];
    const float* W1  = (const float*)d_in[3];
    const float* b1  = (const float*)d_in[4];
    const float* W2  = (const float*)d_in[5];
    const float* b2  = (const float*)d_in[6];
    const float* W3  = (const float*)d_in[7];
    const float* b3  = (const float*)d_in[8];
    const float* g1  = (const float*)d_in[9];
    const float* be1 = (const float*)d_in[10];
    const float* m1  = (const float*)d_in[11];
    const float* v1  = (const float*)d_in[12];
    const float* g2  = (const float*)d_in[13];
    const float* be2 = (const float*)d_in[14];
    const float* m2  = (const float*)d_in[15];
    const float* v2  = (const float*)d_in[16];
    const float* g3  = (const float*)d_in[17];
    const float* be3 = (const float*)d_in[18];
    const float* m3  = (const float*)d_in[19];
    const float* v3  = (const float*)d_in[20];
    const float* Wc1 = (const float*)d_in[21];
    const float* bc1 = (const float*)d_in[22];
    const float* Wc2 = (const float*)d_in[23];
    const float* bc2 = (const float*)d_in[24];
    float* out = (float*)d_out;

    const int N = in_sizes[2];          // 50000  (must be < 65536 for ushort ssrc)
    const int E = in_sizes[1] / 2;      // 1600000
    const int* src = ei;
    const int* dst = ei + E;

    const int nbkt = (N + 511) >> 9;
    const int cap  = (((E / nbkt) * 5) / 4 + 255) & ~255;   // fixed bucket capacity

    char* w = (char*)d_ws;
    int*   row_off = (int*)w;             w += align256((size_t)N * 4);
    unsigned short* deg = (unsigned short*)w; w += align256((size_t)N * 2);
    float* inv     = (float*)w;           w += align256((size_t)N * 4);
    int*   order   = (int*)w;             w += align256((size_t)N * 4);
    unsigned short* ssrc = (unsigned short*)w; w += align256((size_t)nbkt * cap * 2);
    unsigned int* pairs = (unsigned int*)w; w += align256((size_t)nbkt * cap * 4);
    int*   bucket_cursor = (int*)w;       w += align256((size_t)NBKT_MAX * 4);
    int*   dhist   = (int*)w;             w += align256((size_t)DBINS * 4);
    int*   dcursor = (int*)w;             w += align256((size_t)DBINS * 4);
    float* scsh    = (float*)w;           w += align256((size_t)6 * HDIM * 4);
    unsigned short* W1p = (unsigned short*)w;  w += align256((size_t)FDIM_IN * HDIM * 2);
    unsigned short* W2p = (unsigned short*)w;  w += align256((size_t)HDIM * HDIM * 2);
    unsigned short* W3p = (unsigned short*)w;  w += align256((size_t)HDIM * HDIM * 2);
    unsigned short* bufA_bf = (unsigned short*)w;  w += align256((size_t)N * HDIM * 2);
    char* regionR = w;                    // reused region
    unsigned short* xs_sl = (unsigned short*)regionR;                           // N*128*2 slabs
    unsigned short* hs_sl = (unsigned short*)(regionR + align256((size_t)N * FDIM_IN * 2)); // N*160*2 slabs
    float* bufB = (float*)regionR;        // final h3 fp32 (aliases xs/hs, both dead by then)
    float* sc1 = scsh, *sh1 = scsh + 160, *sc2 = scsh + 320, *sh2 = scsh + 480,
         * sc3 = scsh + 640, *sh3 = scsh + 800;

    // preprocessing: fixed-capacity dst sort -> CSR (row_off, deg, inv, ssrc); degree order
    init_kernel<<<1, 1024, 0, stream>>>(bucket_cursor, dhist, nbkt, cap);
    part_kernel<<<256, 256, 0, stream>>>(src, dst, bucket_cursor, pairs, E, cap);
    bucket_csr_kernel<<<nbkt, 1024, 0, stream>>>(pairs, bucket_cursor, row_off, deg, inv, ssrc, N, cap);
    dhist_kernel<<<128, 256, 0, stream>>>(deg, dhist, N);
    dscan_kernel<<<1, 1024, 0, stream>>>(dhist, dcursor);
    dorder_kernel<<<(N + 255) / 256, 256, 0, stream>>>(deg, dcursor, order, N);

    prep_kernel<<<1, 256, 0, stream>>>(b1, g1, be1, m1, v1, sc1, sh1);
    prep_kernel<<<1, 256, 0, stream>>>(b2, g2, be2, m2, v2, sc2, sh2);
    prep_kernel<<<1, 256, 0, stream>>>(b3, g3, be3, m3, v3, sc3, sh3);
    pack_w_kernel<128><<<(128 * 160 + 255) / 256, 256, 0, stream>>>(W1, W1p);
    pack_w_kernel<160><<<(160 * 160 + 255) / 256, 256, 0, stream>>>(W2, W2p);
    pack_w_kernel<160><<<(160 * 160 + 255) / 256, 256, 0, stream>>>(W3, W3p);

    int gAgg128 = ((N + 63) / 64) * 4;   // 4 waves x 16 nodes per block, x4 slices
    int gAgg160 = ((N + 47) / 48) * 4;   // 4 waves x 12 nodes per block, x4 slices
    int gGemm = (N + 63) / 64;

    // layer 1: xs slabs = bf16(x*inv); agg; MFMA GEMM(K=128)+BN+ReLU -> hs slabs
    scale_slab_kernel<<<(N * 32 + 255) / 256, 256, 0, stream>>>(x, inv, xs_sl, N);
    agg_slab2_kernel<128><<<gAgg128, 256, 0, stream>>>(xs_sl, row_off, deg, order, ssrc, bufA_bf, N);
    mfma_gemm_kernel<128, 1><<<gGemm, 256, 0, stream>>>(bufA_bf, W1p, sc1, sh1, inv, nullptr, hs_sl, N);
    // layer 2
    agg_slab2_kernel<160><<<gAgg160, 256, 0, stream>>>(hs_sl, row_off, deg, order, ssrc, bufA_bf, N);
    mfma_gemm_kernel<160, 1><<<gGemm, 256, 0, stream>>>(bufA_bf, W2p, sc2, sh2, inv, nullptr, hs_sl, N);
    // layer 3: fp32 unscaled h3 for pooling (bufB aliases dead xs/hs region)
    agg_slab2_kernel<160><<<gAgg160, 256, 0, stream>>>(hs_sl, row_off, deg, order, ssrc, bufA_bf, N);
    mfma_gemm_kernel<160, 0><<<gGemm, 256, 0, stream>>>(bufA_bf, W3p, sc3, sh3, inv, bufB, nullptr, N);

    pool_head_kernel<<<N_GRAPHS, 256, 0, stream>>>(bufB, batch, Wc1, bc1, Wc2, bc2, out, N);
}

// Round 11
// 480.240 us; speedup vs baseline: 1.2541x; 1.2541x over previous
//
#include <hip/hip_runtime.h>

#define N_NODES   50000
#define N_EDGES   1600000
#define FDIM_IN   128
#define HDIM      160
#define N_GRAPHS  512
#define BN_EPS    1e-5f
#define NBKT_MAX  128           // coarse dst buckets of 512 nodes (N<=65536)
#define DBINS     1024          // degree-sort bins

typedef short  frag8 __attribute__((ext_vector_type(8)));   // 8 x bf16
typedef float  facc4 __attribute__((ext_vector_type(4)));   // 4 x f32

// ---------------- bf16 helpers ----------------

__device__ __forceinline__ unsigned short f2bf(float f) {
    unsigned int u = __float_as_uint(f);
    return (unsigned short)((u + 0x7FFFu + ((u >> 16) & 1u)) >> 16);
}

__device__ __forceinline__ unsigned int pack2(float lo, float hi) {
    return (unsigned int)f2bf(lo) | ((unsigned int)f2bf(hi) << 16);
}

__device__ __forceinline__ void addpk8(float* acc, uint4 r) {
    acc[0] += __uint_as_float(r.x << 16);
    acc[1] += __uint_as_float(r.x & 0xFFFF0000u);
    acc[2] += __uint_as_float(r.y << 16);
    acc[3] += __uint_as_float(r.y & 0xFFFF0000u);
    acc[4] += __uint_as_float(r.z << 16);
    acc[5] += __uint_as_float(r.z & 0xFFFF0000u);
    acc[6] += __uint_as_float(r.w << 16);
    acc[7] += __uint_as_float(r.w & 0xFFFF0000u);
}

// ---------------- init: fixed-capacity bucket cursors + degree-hist zero ----------------

__global__ __launch_bounds__(1024) void init_kernel(int* __restrict__ bucket_cursor,
                                                    int* __restrict__ dhist,
                                                    int nbkt, int cap) {
    int t = threadIdx.x;
    if (t < nbkt) bucket_cursor[t] = t * cap;
    if (t < DBINS) dhist[t] = 0;
}

// level 1: partition packed (src<<9 | dst&511) into fixed-capacity bucket regions
__global__ __launch_bounds__(256) void part_kernel(const int* __restrict__ src,
                                                   const int* __restrict__ dst,
                                                   int* __restrict__ bucket_cursor,
                                                   unsigned int* __restrict__ pairs,
                                                   int E, int cap) {
    __shared__ int bcnt[NBKT_MAX], bbase[NBKT_MAX], lc[NBKT_MAX];
    int tid = threadIdx.x;
    int per = (E + gridDim.x - 1) / gridDim.x;
    int beg = blockIdx.x * per;
    int end = min(beg + per, E);
    if (tid < NBKT_MAX) { bcnt[tid] = 0; lc[tid] = 0; }
    __syncthreads();
    for (int e = beg + tid; e < end; e += 256)
        atomicAdd(&bcnt[dst[e] >> 9], 1);
    __syncthreads();
    if (tid < NBKT_MAX)
        bbase[tid] = bcnt[tid] ? atomicAdd(&bucket_cursor[tid], bcnt[tid]) : 0;
    __syncthreads();
    for (int e = beg + tid; e < end; e += 256) {
        int d = dst[e];
        int b = d >> 9;
        int pos = bbase[b] + atomicAdd(&lc[b], 1);
        if (pos < (b + 1) * cap)   // statistically impossible overflow guard
            pairs[pos] = ((unsigned int)src[e] << 9) | (unsigned int)(d & 511);
    }
}

// level 2: per-bucket exact CSR build + local scatter; per-node segments in ssrc
// are aligned to 4 entries (8B) so the agg can load 4 edge ids per uint2.
__global__ __launch_bounds__(1024) void bucket_csr_kernel(const unsigned int* __restrict__ pairs,
                                                          const int* __restrict__ bucket_cursor,
                                                          int* __restrict__ row_off,
                                                          unsigned short* __restrict__ deg,
                                                          float* __restrict__ inv,
                                                          unsigned short* __restrict__ ssrc,
                                                          int n, int cap) {
    __shared__ int h[512];
    __shared__ int ws[8];
    int tid = threadIdx.x;
    int b = blockIdx.x;
    int node0 = b << 9;
    int beg = b * cap;                       // 4-entry aligned (cap % 256 == 0)
    int end = min(bucket_cursor[b], (b + 1) * cap);
    if (tid < 512) h[tid] = 0;
    __syncthreads();
    for (int j = beg + tid; j < end; j += 1024)
        atomicAdd(&h[pairs[j] & 511], 1);
    __syncthreads();
    int cntv = (tid < 512) ? h[tid] : 0;
    int acnt = (cntv + 3) & ~3;              // aligned segment length
    __syncthreads();
    int lane = tid & 63, wid = tid >> 6;
    int incl = acnt;
    #pragma unroll
    for (int off = 1; off < 64; off <<= 1) {
        int u = __shfl_up(incl, off);
        if (lane >= off) incl += u;
    }
    if (tid < 512 && lane == 63) ws[wid] = incl;
    __syncthreads();
    if (tid == 0) {
        int r = 0;
        #pragma unroll
        for (int i = 0; i < 8; ++i) { int t = ws[i]; ws[i] = r; r += t; }
    }
    __syncthreads();
    int excl = (tid < 512) ? (ws[wid] + incl - acnt) : 0;
    if (tid < 512) {
        int node = node0 + tid;
        if (node < n) {
            row_off[node] = beg + excl;
            deg[node] = (unsigned short)cntv;
            inv[node] = rsqrtf((float)(cntv + 1));   // +1 = self loop
        }
        h[tid] = excl;
    }
    __syncthreads();
    for (int j = beg + tid; j < end; j += 1024) {
        unsigned int p = pairs[j];
        int pos = beg + atomicAdd(&h[p & 511], 1);
        ssrc[pos] = (unsigned short)(p >> 9);
    }
}

// ---------------- degree ordering (two-level counting sort of nodes by degree) ----------------

__global__ __launch_bounds__(256) void dhist_kernel(const unsigned short* __restrict__ deg,
                                                    int* __restrict__ dhist, int n) {
    __shared__ int h[DBINS];
    int tid = threadIdx.x;
    for (int i = tid; i < DBINS; i += 256) h[i] = 0;
    __syncthreads();
    for (int i = blockIdx.x * 256 + tid; i < n; i += gridDim.x * 256)
        atomicAdd(&h[min((int)deg[i], DBINS - 1)], 1);
    __syncthreads();
    for (int i = tid; i < DBINS; i += 256)
        if (h[i]) atomicAdd(&dhist[i], h[i]);
}

__global__ __launch_bounds__(1024) void dscan_kernel(const int* __restrict__ dhist,
                                                     int* __restrict__ dcursor) {
    __shared__ int ws[16];
    int t = threadIdx.x;
    int v = dhist[t];
    int lane = t & 63, wid = t >> 6;
    int incl = v;
    #pragma unroll
    for (int off = 1; off < 64; off <<= 1) {
        int u = __shfl_up(incl, off);
        if (lane >= off) incl += u;
    }
    if (lane == 63) ws[wid] = incl;
    __syncthreads();
    if (t == 0) {
        int r = 0;
        #pragma unroll
        for (int i = 0; i < 16; ++i) { int x = ws[i]; ws[i] = r; r += x; }
    }
    __syncthreads();
    dcursor[t] = ws[wid] + incl - v;    // exclusive prefix
}

// two-level: per-block LDS rank + one global atomic per (block, occupied bin)
__global__ __launch_bounds__(256) void dorder_kernel(const unsigned short* __restrict__ deg,
                                                     int* __restrict__ dcursor,
                                                     int* __restrict__ order, int n) {
    __shared__ int lh[DBINS];
    __shared__ int lbase[DBINS];
    int tid = threadIdx.x;
    for (int i = tid; i < DBINS; i += 256) lh[i] = 0;
    __syncthreads();
    int i = blockIdx.x * 256 + tid;
    int bin = 0, rank = 0;
    if (i < n) {
        bin = min((int)deg[i], DBINS - 1);
        rank = atomicAdd(&lh[bin], 1);
    }
    __syncthreads();
    for (int b = tid; b < DBINS; b += 256)
        lbase[b] = lh[b] ? atomicAdd(&dcursor[b], lh[b]) : 0;
    __syncthreads();
    if (i < n)
        order[lbase[bin] + rank] = i;
}

// ---------------- BN fold ----------------

__global__ void prep_kernel(const float* __restrict__ b, const float* __restrict__ g,
                            const float* __restrict__ be, const float* __restrict__ m,
                            const float* __restrict__ v, float* __restrict__ sc,
                            float* __restrict__ sh) {
    int t = threadIdx.x;
    if (t < HDIM) {
        float s = g[t] * rsqrtf(v[t] + BN_EPS);
        sc[t] = s;
        sh[t] = (b[t] - m[t]) * s + be[t];
    }
}

// ---------------- weight pack: W fp32 [K x 160] -> bf16 MFMA B-fragment order ----------------

template <int K>
__global__ __launch_bounds__(256) void pack_w_kernel(const float* __restrict__ W,
                                                     unsigned short* __restrict__ out) {
    int tid = blockIdx.x * 256 + threadIdx.x;
    if (tid >= K * 160) return;
    int j = tid & 7;
    int l = (tid >> 3) & 63;
    int u = (tid >> 9) % 10;
    int t = tid / 5120;
    int k = t * 32 + (l >> 4) * 8 + j;
    int nn = u * 16 + (l & 15);
    out[tid] = f2bf(W[k * 160 + nn]);
}

// ---------------- pre-scale + pack into 4 channel slabs (C=128, SLICE=32) ----------------

__global__ __launch_bounds__(256) void scale_slab_kernel(const float* __restrict__ x,
                                                         const float* __restrict__ inv,
                                                         unsigned short* __restrict__ slabs,
                                                         int n) {
    int i = blockIdx.x * 256 + threadIdx.x;      // float4 index over n*32
    if (i < n * 32) {
        int node = i >> 5;
        int f = i & 31;                          // float4 within row
        int s = f >> 3;                          // slice (8 float4 per slice)
        int o = f & 7;
        float w = inv[node];
        float4 v = ((const float4*)x)[i];
        ushort4 ov;
        ov.x = f2bf(v.x * w); ov.y = f2bf(v.y * w);
        ov.z = f2bf(v.z * w); ov.w = f2bf(v.w * w);
        *(ushort4*)(slabs + (size_t)s * n * 32 + (size_t)node * 32 + o * 4) = ov;
    }
}

// ---------------- XCD-affine slab aggregation, group-per-node, degree-sorted ----------------
// slabs: 4 slabs of N*SLICE bf16 (pre-scaled by inv[src]); SLICE = C/4.
// Each LPE-lane group owns ONE node: no cross-group combine. Edge ids loaded
// 4-at-a-time (uint2, segments 4-entry aligned); inner loop unrolled 4 for ILP.
// Degree-sorted order[] equalizes trip counts within a wave. slice = blockIdx&3
// keeps each XCD's gathers inside one <=4MB slab (L2-resident; heuristic only).

template <int C>
__global__ __launch_bounds__(256) void agg_slab2_kernel(const unsigned short* __restrict__ slabs,
                                                        const int* __restrict__ row_off,
                                                        const unsigned short* __restrict__ deg,
                                                        const int* __restrict__ order,
                                                        const unsigned short* __restrict__ ssrc,
                                                        unsigned short* __restrict__ out, int n) {
    constexpr int SLICE = C / 4;        // 40 or 32 channels
    constexpr int LPE   = SLICE / 8;    // lanes per node (uint4 = 8 ch): 5 or 4
    constexpr int G     = 64 / LPE;     // nodes per wave: 12 or 16
    int wave = threadIdx.x >> 6;
    int lane = threadIdx.x & 63;
    int slice = blockIdx.x & 3;
    int nb = blockIdx.x >> 2;
    int g  = lane / LPE;
    int cl = lane - g * LPE;
    const uint4* slab = (const uint4*)(slabs + (size_t)slice * n * SLICE);  // row = LPE uint4

    int gidx = nb * (4 * G) + wave * G + g;
    bool act = (g < G) && (gidx < n);
    int node = 0, beg = 0, dg = 0;
    if (act) {
        node = order[gidx];
        beg  = row_off[node];
        dg   = (int)deg[node];
    }
    float acc[8] = {0.f, 0.f, 0.f, 0.f, 0.f, 0.f, 0.f, 0.f};
    if (act) {   // self-loop term
        uint4 r = slab[(size_t)node * LPE + cl];
        addpk8(acc, r);
    }
    const uint2* el = (const uint2*)(ssrc + beg);   // beg is 4-entry aligned
    int j = 0;
    for (; j + 4 <= dg; j += 4) {
        uint2 e = el[j >> 2];
        int s0 = e.x & 0xFFFF, s1 = e.x >> 16;
        int s2 = e.y & 0xFFFF, s3 = e.y >> 16;
        uint4 r0 = slab[(size_t)s0 * LPE + cl];
        uint4 r1 = slab[(size_t)s1 * LPE + cl];
        uint4 r2 = slab[(size_t)s2 * LPE + cl];
        uint4 r3 = slab[(size_t)s3 * LPE + cl];
        addpk8(acc, r0);
        addpk8(acc, r1);
        addpk8(acc, r2);
        addpk8(acc, r3);
    }
    for (; j < dg; ++j) {
        uint4 r = slab[(size_t)ssrc[beg + j] * LPE + cl];
        addpk8(acc, r);
    }
    if (act) {
        float wi = rsqrtf((float)(dg + 1));
        uint4 o;
        o.x = pack2(acc[0] * wi, acc[1] * wi);
        o.y = pack2(acc[2] * wi, acc[3] * wi);
        o.z = pack2(acc[4] * wi, acc[5] * wi);
        o.w = pack2(acc[6] * wi, acc[7] * wi);
        *(uint4*)(out + (size_t)node * C + slice * SLICE + cl * 8) = o;
    }
}

// ---------------- MFMA GEMM: relu((A[n x K]bf16 @ B[K x 160]bf16) * sc + sh) ----------------
// OUTMODE 0: fp32 row-major out. OUTMODE 1: bf16 out scaled by inv[row], written to
// 4 channel slabs of SLICE=40 (layer-2/3 agg input layout).

template <int K, int OUTMODE>
__global__ __launch_bounds__(256) void mfma_gemm_kernel(const unsigned short* __restrict__ A,
                                                        const unsigned short* __restrict__ Bp,
                                                        const float* __restrict__ sc,
                                                        const float* __restrict__ sh,
                                                        const float* __restrict__ inv,
                                                        float* __restrict__ CoutF,
                                                        unsigned short* __restrict__ CoutB,
                                                        int n) {
    constexpr int KT = K / 32;
    int tid = threadIdx.x;
    int wave = tid >> 6, lane = tid & 63;
    int row0 = blockIdx.x * 64 + wave * 16;
    int m = lane & 15, q = lane >> 4;

    int arow = row0 + m;
    int arowc = (arow < n) ? arow : (n - 1);
    const frag8* Abase = (const frag8*)(A + (size_t)arowc * K);   // frag idx = t*4 + q
    const frag8* Bbase = (const frag8*)Bp;                        // frag idx = (t*10+u)*64 + lane

    facc4 acc[10];
    #pragma unroll
    for (int u = 0; u < 10; ++u) acc[u] = (facc4){0.f, 0.f, 0.f, 0.f};

    #pragma unroll
    for (int t = 0; t < KT; ++t) {
        frag8 af = Abase[t * 4 + q];
        #pragma unroll
        for (int u = 0; u < 10; ++u) {
            frag8 bf = Bbase[(t * 10 + u) * 64 + lane];
            acc[u] = __builtin_amdgcn_mfma_f32_16x16x32_bf16(af, bf, acc[u], 0, 0, 0);
        }
    }

    // D layout: col = lane&15 (within tile), row = q*4 + reg
    #pragma unroll
    for (int u = 0; u < 10; ++u) {
        int c = u * 16 + m;
        float scv = sc[c], shv = sh[c];
        int s = c / 40, o = c - s * 40;   // slab / offset (OUTMODE 1)
        #pragma unroll
        for (int r = 0; r < 4; ++r) {
            int rr = row0 + q * 4 + r;
            if (rr < n) {
                float v = fmaxf(acc[u][r] * scv + shv, 0.f);
                if (OUTMODE == 1) {
                    CoutB[(size_t)s * n * 40 + (size_t)rr * 40 + o] = f2bf(v * inv[rr]);
                } else {
                    CoutF[(size_t)rr * 160 + c] = v;
                }
            }
        }
    }
}

// ---------------- mean pool (sorted batch) + MLP head ----------------

__global__ __launch_bounds__(256) void pool_head_kernel(const float* __restrict__ h,
                                                        const int* __restrict__ batch,
                                                        const float* __restrict__ Wc1,
                                                        const float* __restrict__ bc1,
                                                        const float* __restrict__ Wc2,
                                                        const float* __restrict__ bc2,
                                                        float* __restrict__ out, int n) {
    __shared__ float pooled[160];
    __shared__ float z[80];
    __shared__ int range[2];
    int g = blockIdx.x;
    int t = threadIdx.x;
    if (t < 2) {
        int target = g + t;
        int lo = 0, hi = n;
        while (lo < hi) {
            int mid = (lo + hi) >> 1;
            if (batch[mid] < target) lo = mid + 1; else hi = mid;
        }
        range[t] = lo;
    }
    __syncthreads();
    int lo = range[0], hi = range[1];
    if (t < 160) {
        float s = 0.f;
        for (int r = lo; r < hi; ++r) s += h[(size_t)r * 160 + t];
        pooled[t] = s / fmaxf((float)(hi - lo), 1.f);
    }
    __syncthreads();
    if (t < 80) {
        float s = bc1[t];
        for (int k = 0; k < 160; ++k) s += pooled[k] * Wc1[k * 80 + t];
        z[t] = fmaxf(s, 0.f);
    }
    __syncthreads();
    if (t < 2) {
        float s = bc2[t];
        for (int k = 0; k < 80; ++k) s += z[k] * Wc2[k * 2 + t];
        out[g * 2 + t] = s;
    }
}

// ---------------- launch ----------------

static inline size_t align256(size_t x) { return (x + 255) & ~(size_t)255; }

extern "C" void kernel_launch(void* const* d_in, const int* in_sizes, int n_in,
                              void* d_out, int out_size, void* d_ws, size_t ws_size,
                              hipStream_t stream) {
    const float* x   = (const float*)d_in[0];
    const int* ei    = (const int*)d_in[1];
    const int* batch = (const int*)d_in[2];
    const float* W1  = (const float*)d_in[3];
    const float* b1  = (const float*)d_in[4];
    const float* W2  = (const float*)d_in[5];
    const float* b2  = (const float*)d_in[6];
    const float* W3  = (const float*)d_in[7];
    const float* b3  = (const float*)d_in[8];
    const float* g1  = (const float*)d_in[9];
    const float* be1 = (const float*)d_in[10];
    const float* m1  = (const float*)d_in[11];
    const float* v1  = (const float*)d_in[12];
    const float* g2  = (const float*)d_in[13];
    const float* be2 = (const float*)d_in[14];
    const float* m2  = (const float*)d_in[15];
    const float* v2  = (const float*)d_in[16];
    const float* g3  = (const float*)d_in[17];
    const float* be3 = (const float*)d_in[18];
    const float* m3  = (const float*)d_in[19];
    const float* v3  = (const float*)d_in[20];
    const float* Wc1 = (const float*)d_in[21];
    const float* bc1 = (const float*)d_in[22];
    const float* Wc2 = (const float*)d_in[23];
    const float* bc2 = (const float*)d_in[24];
    float* out = (float*)d_out;

    const int N = in_sizes[2];          // 50000  (must be < 65536 for ushort ssrc)
    const int E = in_sizes[1] / 2;      // 1600000
    const int* src = ei;
    const int* dst = ei + E;

    const int nbkt = (N + 511) >> 9;
    const int cap  = (((E / nbkt) * 5) / 4 + 255) & ~255;   // fixed bucket capacity

    char* w = (char*)d_ws;
    int*   row_off = (int*)w;             w += align256((size_t)N * 4);
    unsigned short* deg = (unsigned short*)w; w += align256((size_t)N * 2);
    float* inv     = (float*)w;           w += align256((size_t)N * 4);
    int*   order   = (int*)w;             w += align256((size_t)N * 4);
    unsigned short* ssrc = (unsigned short*)w; w += align256((size_t)nbkt * cap * 2);
    unsigned int* pairs = (unsigned int*)w; w += align256((size_t)nbkt * cap * 4);
    int*   bucket_cursor = (int*)w;       w += align256((size_t)NBKT_MAX * 4);
    int*   dhist   = (int*)w;             w += align256((size_t)DBINS * 4);
    int*   dcursor = (int*)w;             w += align256((size_t)DBINS * 4);
    float* scsh    = (float*)w;           w += align256((size_t)6 * HDIM * 4);
    unsigned short* W1p = (unsigned short*)w;  w += align256((size_t)FDIM_IN * HDIM * 2);
    unsigned short* W2p = (unsigned short*)w;  w += align256((size_t)HDIM * HDIM * 2);
    unsigned short* W3p = (unsigned short*)w;  w += align256((size_t)HDIM * HDIM * 2);
    unsigned short* bufA_bf = (unsigned short*)w;  w += align256((size_t)N * HDIM * 2);
    char* regionR = w;                    // reused region
    unsigned short* xs_sl = (unsigned short*)regionR;                           // N*128*2 slabs
    unsigned short* hs_sl = (unsigned short*)(regionR + align256((size_t)N * FDIM_IN * 2)); // N*160*2 slabs
    float* bufB = (float*)regionR;        // final h3 fp32 (aliases xs/hs, both dead by then)
    float* sc1 = scsh, *sh1 = scsh + 160, *sc2 = scsh + 320, *sh2 = scsh + 480,
         * sc3 = scsh + 640, *sh3 = scsh + 800;

    // preprocessing: fixed-capacity dst sort -> CSR (row_off, deg, inv, ssrc); degree order
    init_kernel<<<1, 1024, 0, stream>>>(bucket_cursor, dhist, nbkt, cap);
    part_kernel<<<256, 256, 0, stream>>>(src, dst, bucket_cursor, pairs, E, cap);
    bucket_csr_kernel<<<nbkt, 1024, 0, stream>>>(pairs, bucket_cursor, row_off, deg, inv, ssrc, N, cap);
    dhist_kernel<<<128, 256, 0, stream>>>(deg, dhist, N);
    dscan_kernel<<<1, 1024, 0, stream>>>(dhist, dcursor);
    dorder_kernel<<<(N + 255) / 256, 256, 0, stream>>>(deg, dcursor, order, N);

    prep_kernel<<<1, 256, 0, stream>>>(b1, g1, be1, m1, v1, sc1, sh1);
    prep_kernel<<<1, 256, 0, stream>>>(b2, g2, be2, m2, v2, sc2, sh2);
    prep_kernel<<<1, 256, 0, stream>>>(b3, g3, be3, m3, v3, sc3, sh3);
    pack_w_kernel<128><<<(128 * 160 + 255) / 256, 256, 0, stream>>>(W1, W1p);
    pack_w_kernel<160><<<(160 * 160 + 255) / 256, 256, 0, stream>>>(W2, W2p);
    pack_w_kernel<160><<<(160 * 160 + 255) / 256, 256, 0, stream>>>(W3, W3p);

    int gAgg128 = ((N + 63) / 64) * 4;   // 4 waves x 16 nodes per block, x4 slices
    int gAgg160 = ((N + 47) / 48) * 4;   // 4 waves x 12 nodes per block, x4 slices
    int gGemm = (N + 63) / 64;

    // layer 1: xs slabs = bf16(x*inv); agg; MFMA GEMM(K=128)+BN+ReLU -> hs slabs
    scale_slab_kernel<<<(N * 32 + 255) / 256, 256, 0, stream>>>(x, inv, xs_sl, N);
    agg_slab2_kernel<128><<<gAgg128, 256, 0, stream>>>(xs_sl, row_off, deg, order, ssrc, bufA_bf, N);
    mfma_gemm_kernel<128, 1><<<gGemm, 256, 0, stream>>>(bufA_bf, W1p, sc1, sh1, inv, nullptr, hs_sl, N);
    // layer 2
    agg_slab2_kernel<160><<<gAgg160, 256, 0, stream>>>(hs_sl, row_off, deg, order, ssrc, bufA_bf, N);
    mfma_gemm_kernel<160, 1><<<gGemm, 256, 0, stream>>>(bufA_bf, W2p, sc2, sh2, inv, nullptr, hs_sl, N);
    // layer 3: fp32 unscaled h3 for pooling (bufB aliases dead xs/hs region)
    agg_slab2_kernel<160><<<gAgg160, 256, 0, stream>>>(hs_sl, row_off, deg, order, ssrc, bufA_bf, N);
    mfma_gemm_kernel<160, 0><<<gGemm, 256, 0, stream>>>(bufA_bf, W3p, sc3, sh3, inv, bufB, nullptr, N);

    pool_head_kernel<<<N_GRAPHS, 256, 0, stream>>>(bufB, batch, Wc1, bc1, Wc2, bc2, out, N);
}